// Round 5
// baseline (201.724 us; speedup 1.0000x reference)
//
#include <hip/hip_runtime.h>
#include <hip/hip_fp16.h>

typedef float    f4 __attribute__((ext_vector_type(4)));
typedef unsigned u4 __attribute__((ext_vector_type(4)));

__device__ __forceinline__ float2 cadd(float2 a, float2 b) { return make_float2(a.x + b.x, a.y + b.y); }
__device__ __forceinline__ float2 csub(float2 a, float2 b) { return make_float2(a.x - b.x, a.y - b.y); }
__device__ __forceinline__ float2 cmul(float2 w, float2 z) {
    return make_float2(w.x * z.x - w.y * z.y, w.x * z.y + w.y * z.x);
}
__device__ __forceinline__ unsigned pk(float2 z) {
    __half2 h = __floats2half2_rn(z.x, z.y);
    return *reinterpret_cast<unsigned*>(&h);
}
__device__ __forceinline__ float2 upk(unsigned u) {
    __half2 h = *reinterpret_cast<__half2*>(&u);
    return __half22float2(h);
}

__host__ __device__ constexpr unsigned crev(unsigned x, int bits) {
    unsigned r = 0;
    for (int k = 0; k < bits; ++k) r |= ((x >> k) & 1u) << (bits - 1 - k);
    return r;
}

// Butterfly network (DIF):
//   stage t (0..22): pairs (i, i + 2^(22-t)); z'[i] = z[i] + w*z[i+D]; z'[i+D] = z[i] - w*z[i+D]
//   w = weight[ bitrev_t(i >> (23-t)) * 2^(22-t) ];  final: out[rev23(i)] = z[i]
// Split: A: t=0..7 (bits 22..15, LDS tile)
//        B: t=8..12 (bits 14..10, radix-32 pure-register streaming, block-uniform twiddles)
//        C: t=13..22 (bits 9..0, 1024-pt FFTs; 8 bit-rev-selected chunks/block -> dense stores)
// v5 = v4 with nontemporal builtins routed through clang ext-vector types (HIP uint4/float4
//      wrappers are rejected by __builtin_nontemporal_*).

__global__ __launch_bounds__(256) void fft_pass_a(const float* __restrict__ in,
                                                  const float2* __restrict__ wt,
                                                  uint4* __restrict__ outp)
{
    __shared__ float2 L[4096];   // [g*16 + c], 32 KB
    const int tid = threadIdx.x;
    const int l0  = blockIdx.x << 4;
    const int c   = tid & 15;
    const int qb  = tid >> 4;

    float2 pw1[4], pw2a[4], pw2b[4];
#pragma unroll
    for (int k = 0; k < 4; ++k) { pw1[k] = wt[0]; pw2a[k] = wt[0]; pw2b[k] = wt[1 << 21]; }

    {
        const int c4 = tid & 3, gg = tid >> 2;
#pragma unroll
        for (int k = 0; k < 4; ++k) {
            const int g = gg + (k << 6);
            const f4 v = __builtin_nontemporal_load(
                reinterpret_cast<const f4*>(in + ((size_t)g << 15) + l0 + (c4 << 2)));
            const int base = (g << 4) + (c4 << 2);
            L[base + 0] = make_float2(v[0], 0.f);
            L[base + 1] = make_float2(v[1], 0.f);
            L[base + 2] = make_float2(v[2], 0.f);
            L[base + 3] = make_float2(v[3], 0.f);
        }
    }
    __syncthreads();

#pragma unroll
    for (int rho = 0; rho < 4; ++rho) {
        const int s = rho << 1, H = 128 >> s, Q = H >> 1, lo = 6 - s;
        float2 nw1[4], nw2a[4], nw2b[4];
        if (rho < 3) {
            const int s2 = s + 2, lo2 = 6 - s2;
#pragma unroll
            for (int k = 0; k < 4; ++k) {
                const int qi = (qb << 2) + k;
                const int b  = ((qi >> lo2) << (lo2 + 2)) | (qi & ((1 << lo2) - 1));
                const int jl = (int)(__brev((unsigned)(b >> (8 - s2))) >> (32 - s2));
                const int e  = jl << (21 - s2);
                nw1[k] = wt[e << 1]; nw2a[k] = wt[e]; nw2b[k] = wt[e + (1 << 21)];
            }
        }
#pragma unroll
        for (int k = 0; k < 4; ++k) {
            const int qi = (qb << 2) + k;
            const int b  = ((qi >> lo) << (lo + 2)) | (qi & ((1 << lo) - 1));
            const int iA = (b << 4) + c;
            const float2 A  = L[iA];
            const float2 Bv = L[iA + (Q << 4)];
            const float2 Cv = L[iA + (H << 4)];
            const float2 Dv = L[iA + ((H + Q) << 4)];
            const float2 pC = cmul(pw1[k], Cv), pD = cmul(pw1[k], Dv);
            const float2 tA = cadd(A, pC),  tC = csub(A, pC);
            const float2 tB = cadd(Bv, pD), tD = csub(Bv, pD);
            const float2 p2 = cmul(pw2a[k], tB);
            const float2 p3 = cmul(pw2b[k], tD);
            L[iA]                  = cadd(tA, p2);
            L[iA + (Q << 4)]       = csub(tA, p2);
            L[iA + (H << 4)]       = cadd(tC, p3);
            L[iA + ((H + Q) << 4)] = csub(tC, p3);
        }
        __syncthreads();
        if (rho < 3) {
#pragma unroll
            for (int k = 0; k < 4; ++k) { pw1[k] = nw1[k]; pw2a[k] = nw2a[k]; pw2b[k] = nw2b[k]; }
        }
    }

    {
        const int c4 = tid & 3, gg = tid >> 2;
#pragma unroll
        for (int k = 0; k < 4; ++k) {
            const int g  = gg + (k << 6);
            const int li = (g << 4) + (c4 << 2);
            u4 v;
            v[0] = pk(L[li]); v[1] = pk(L[li + 1]); v[2] = pk(L[li + 2]); v[3] = pk(L[li + 3]);
            __builtin_nontemporal_store(v,
                reinterpret_cast<u4*>(&outp[((size_t)g << 13) + (l0 >> 2) + c4]));
        }
    }
}

// ---- pass B: stages 8..12, radix-32 in registers, no LDS ----
// i = (h:8 | m:5 | low:10). Block: h = blk>>2 (uniform), low = (blk&3)<<8 | tid.
__global__ __launch_bounds__(256) void fft_pass_b(const unsigned* __restrict__ in,
                                                  const float2* __restrict__ wt,
                                                  unsigned* __restrict__ out)
{
    const int tid = threadIdx.x;
    const int h   = blockIdx.x >> 2;
    const int low = ((blockIdx.x & 3) << 8) | tid;
    const unsigned hrev = __brev((unsigned)h) >> 24;
    const unsigned base = ((unsigned)h << 15) | (unsigned)low;

    float2 X[32];
#pragma unroll
    for (int m = 0; m < 32; ++m)
        X[m] = upk(__builtin_nontemporal_load(&in[base + ((unsigned)m << 10)]));

#pragma unroll
    for (int s = 0; s < 5; ++s) {
        const int half = 1 << (4 - s);
#pragma unroll
        for (int j = 0; j < 16; ++j) {
            const int mh = j >> (4 - s);
            const int lo = (mh << (5 - s)) | (j & (half - 1));
            const int hi = lo | half;
            const unsigned cr = crev((unsigned)mh, s);
            const float2 w = wt[(((cr << 8) | hrev) << (14 - s))];
            const float2 p = cmul(w, X[hi]);
            X[hi] = csub(X[lo], p);
            X[lo] = cadd(X[lo], p);
        }
    }
#pragma unroll
    for (int m = 0; m < 32; ++m)
        __builtin_nontemporal_store(pk(X[m]), &out[base + ((unsigned)m << 10)]);
}

// ---- pass C: stages 13..22. 8 chunks (1024-pt each) per block, chunk H = rev13(h0*8+lm). ----
// 1024 thr -> 2 blocks/CU = 32 waves/CU. Twiddles for round rho+1 prefetched during rho.
__global__ __launch_bounds__(1024, 8) void fft_pass_c(const uint4* __restrict__ inp4,
                                                      const float2* __restrict__ wt,
                                                      float2* __restrict__ out)
{
    extern __shared__ float2 L[];            // 8 * 1026 * 8 B = 65,664 B
    const int tid = threadIdx.x;
    const int bid = blockIdx.x;
    const int h0  = ((bid & 7) << 7) | (bid >> 3);   // chunked XCD swizzle (1024 = 8*128)
    const int lam = tid & 7;
    const int bq  = tid >> 3;                // 0..127
    const int R   = (h0 << 3) | lam;         // rev13(H) for this lane's chunk

    // ---- staging: 8 chunks x 256 uint4; each thread 2 nontemporal uint4 loads ----
    {
        const int f    = tid & 63;
        const int lm   = (tid >> 6) & 7;
        const int half = tid >> 9;           // 0/1
        const unsigned H = __brev((unsigned)((h0 << 3) | lm)) >> 19;
        const size_t gb = ((size_t)H << 8);
#pragma unroll
        for (int k = 0; k < 2; ++k) {
            const int slot = (half << 7) | (k << 6) | f;
            const u4 v = __builtin_nontemporal_load(
                reinterpret_cast<const u4*>(&inp4[gb + slot]));
            const int base = lm * 1026 + (slot << 2);
            const float2 e0 = upk(v[0]), e1 = upk(v[1]), e2 = upk(v[2]), e3 = upk(v[3]);
            *reinterpret_cast<float4*>(&L[base])     = make_float4(e0.x, e0.y, e1.x, e1.y);
            *reinterpret_cast<float4*>(&L[base + 2]) = make_float4(e2.x, e2.y, e3.x, e3.y);
        }
    }

    // prefetch round-0 twiddles while staging lands
    float2 w1[2], w2a[2], w2b[2];
#pragma unroll
    for (int k = 0; k < 2; ++k) {
        const int e = R << 8;                // rho=0: xr=0
        w1[k] = wt[e << 1]; w2a[k] = wt[e]; w2b[k] = wt[e + (1 << 21)];
    }
    float2 f1[2], f2a[2], f2b[2];            // final-round twiddles (filled during rho=3)
    __syncthreads();

    // rounds rho=0..3: stages (13,14),(15,16),(17,18),(19,20)
#pragma unroll
    for (int rho = 0; rho < 4; ++rho) {
        const int sh = 8 - (rho << 1);       // 8,6,4,2
        const int Q  = 1 << sh;
        const int H2 = Q << 1;
        float2 nw1[2], nw2a[2], nw2b[2];
        if (rho < 3) {
            const int rn = rho + 1, shn = 8 - (rn << 1);
#pragma unroll
            for (int k = 0; k < 2; ++k) {
                const int qi = (k << 7) | bq;
                const unsigned ar = (unsigned)(qi >> shn);
                const unsigned xr = __brev(ar) >> (32 - (rn << 1));
                const int e = (int)(((xr << 13) | (unsigned)R) << shn);
                nw1[k] = wt[e << 1]; nw2a[k] = wt[e]; nw2b[k] = wt[e + (1 << 21)];
            }
        } else {
#pragma unroll
            for (int k = 0; k < 2; ++k) {
                const int qi = (k << 7) | bq;
                const unsigned xr = __brev((unsigned)qi) >> 24;  // rev8
                const int e = (int)((xr << 13) | (unsigned)R);
                f1[k] = wt[e << 1]; f2a[k] = wt[e]; f2b[k] = wt[e + (1 << 21)];
            }
        }
#pragma unroll
        for (int k = 0; k < 2; ++k) {
            const int qi = (k << 7) | bq;    // 0..255
            const int x  = ((qi >> sh) << (sh + 2)) | (qi & (Q - 1));
            const int iA = lam * 1026 + x;
            const float2 A  = L[iA];
            const float2 Bv = L[iA + Q];
            const float2 Cv = L[iA + H2];
            const float2 Dv = L[iA + H2 + Q];
            const float2 pC = cmul(w1[k], Cv), pD = cmul(w1[k], Dv);
            const float2 tA = cadd(A, pC),  tC = csub(A, pC);
            const float2 tB = cadd(Bv, pD), tD = csub(Bv, pD);
            const float2 p2 = cmul(w2a[k], tB);
            const float2 p3 = cmul(w2b[k], tD);
            L[iA]           = cadd(tA, p2);
            L[iA + Q]       = csub(tA, p2);
            L[iA + H2]      = cadd(tC, p3);
            L[iA + H2 + Q]  = csub(tC, p3);
        }
        __syncthreads();
        if (rho < 3) {
#pragma unroll
            for (int k = 0; k < 2; ++k) { w1[k] = nw1[k]; w2a[k] = nw2a[k]; w2b[k] = nw2b[k]; }
        }
    }

    // round rho=4: stages (21,22), legs adjacent -> float4 LDS I/O (twiddles prefetched)
    {
#pragma unroll
        for (int k = 0; k < 2; ++k) {
            const int qi = (k << 7) | bq;            // 0..255
            const int x  = qi << 2;
            const int iA = lam * 1026 + x;
            const float4 g0 = *reinterpret_cast<const float4*>(&L[iA]);
            const float4 g1 = *reinterpret_cast<const float4*>(&L[iA + 2]);
            const float2 A  = make_float2(g0.x, g0.y);
            const float2 Bv = make_float2(g0.z, g0.w);
            const float2 Cv = make_float2(g1.x, g1.y);
            const float2 Dv = make_float2(g1.z, g1.w);
            const float2 pC = cmul(f1[k], Cv), pD = cmul(f1[k], Dv);
            const float2 tA = cadd(A, pC),  tC = csub(A, pC);
            const float2 tB = cadd(Bv, pD), tD = csub(Bv, pD);
            const float2 p2 = cmul(f2a[k], tB);
            const float2 p3 = cmul(f2b[k], tD);
            const float2 rA = cadd(tA, p2), rB = csub(tA, p2);
            const float2 rC = cadd(tC, p3), rD = csub(tC, p3);
            *reinterpret_cast<float4*>(&L[iA])     = make_float4(rA.x, rA.y, rB.x, rB.y);
            *reinterpret_cast<float4*>(&L[iA + 2]) = make_float4(rC.x, rC.y, rD.x, rD.y);
        }
    }
    __syncthreads();

    // store: out[rev10(x)<<13 | h0<<3 | lm] — 8 consecutive lm = one 64 B line (nontemporal)
    {
        const int l2   = (tid & 3) << 1;     // 0,2,4,6
        const int rest = tid >> 2;           // 0..255
#pragma unroll
        for (int k = 0; k < 4; ++k) {
            const int x = (k << 8) | rest;
            const float2 a0 = L[l2 * 1026 + x];
            const float2 a1 = L[(l2 + 1) * 1026 + x];
            const size_t o = ((size_t)(__brev((unsigned)x) >> 22) << 13)
                           | (unsigned)((h0 << 3) | l2);
            f4 sv; sv[0] = a0.x; sv[1] = a0.y; sv[2] = a1.x; sv[3] = a1.y;
            __builtin_nontemporal_store(sv, reinterpret_cast<f4*>(out + o));
        }
    }
}

extern "C" void kernel_launch(void* const* d_in, const int* in_sizes, int n_in,
                              void* d_out, int out_size, void* d_ws, size_t ws_size,
                              hipStream_t stream)
{
    (void)in_sizes; (void)n_in; (void)out_size; (void)ws_size;
    const float*  in = (const float*)d_in[0];
    const float2* wt = (const float2*)d_in[1];
    float2* outc = (float2*)d_out;
    uint4*  buf1 = (uint4*)d_ws;                             // 32 MB packed fp16
    unsigned* buf2 = (unsigned*)((char*)d_ws + (32u << 20)); // 32 MB packed fp16

    static bool attr_done = false;
    if (!attr_done) {
        (void)hipFuncSetAttribute(reinterpret_cast<const void*>(fft_pass_c),
                                  hipFuncAttributeMaxDynamicSharedMemorySize, 8 * 1026 * 8);
        attr_done = true;
    }

    fft_pass_a<<<2048, 256, 0, stream>>>(in, wt, buf1);                             // t=0..7
    fft_pass_b<<<1024, 256, 0, stream>>>((const unsigned*)buf1, wt, buf2);          // t=8..12
    fft_pass_c<<<1024, 1024, 8 * 1026 * 8, stream>>>((const uint4*)buf2, wt, outc); // t=13..22
}